// Round 4
// baseline (152.222 us; speedup 1.0000x reference)
//
#include <hip/hip_runtime.h>

// SelfAttention B=2 S=2048 H=16 E=64, fp32 in/out, bf16 MFMA internally.
// Round 9 = Round 8 with two fault fixes (R8 container died; audit found):
//  (1) proj V epilogue LDS tile stride 20->24 shorts: stride 20 made the
//      ushortx8 (ds_read_b128) reads 8B-aligned for odd e -> mem violation
//      candidate. Stride 24 = 48B keeps every b128 access 16B-aligned.
//  (2) attn epilogue l-reduction restored to R6's exact verified code
//      (Ll[qrow*4 + kblk*2 + hi], no divergent __shfl).
// R8 intent unchanged: attn = R6 structure (46.8us measured); proj
// rewritten for contiguous streaming. total-attn has been a CONSTANT
// ~100us across rounds; old proj (3072 one-head blocks, 256B used per 4KB
// X stride, W re-staged per block) is the suspect vs a ~12us HBM roofline.
// New proj: block = 16 seq x 8 heads x one projection (1536 blocks):
// X-read = 16 x 2KB contiguous (each 4KB input row split across hh=0/1
// sibling blocks), W staged once, W-frags hoisted per wave and reused
// across 8 heads. Output layouts (XOR-swizzled qb/kb/vtb) preserved
// exactly: q/k swizzle key (st*16+s)&7 == s&7 (tiles 8-aligned); vtb
// 64-key window = st>>2, chunk c = (st&3)*2 + cl, key e&7.

#define BATCH 2
#define SEQ   2048
#define NH    16
#define DE    64
#define LDOF  68     // O f32 epilogue stride
#define NKT   (SEQ / 64)
#define LOG2E 1.44269504088896340736f
#define CSHIFT 16.0f

using bf16x8   = __attribute__((ext_vector_type(8))) __bf16;
using bf16x4   = __attribute__((ext_vector_type(4))) __bf16;
using bf16x2   = __attribute__((ext_vector_type(2))) __bf16;
using floatx2  = __attribute__((ext_vector_type(2))) float;
using floatx4  = __attribute__((ext_vector_type(4))) float;
using floatx16 = __attribute__((ext_vector_type(16))) float;
using ushortx4 = __attribute__((ext_vector_type(4))) unsigned short;
using ushortx8 = __attribute__((ext_vector_type(8))) unsigned short;
using uintx4   = __attribute__((ext_vector_type(4))) unsigned int;

__device__ __forceinline__ ushortx4 cvt4(floatx4 f) {
    bf16x4 h = __builtin_convertvector(f, bf16x4);   // RNE packed cvt
    return __builtin_bit_cast(ushortx4, h);
}

__device__ __forceinline__ unsigned int pkbf16(float a, float b) {
    floatx2 f = {a, b};
    return __builtin_bit_cast(unsigned int, __builtin_convertvector(f, bf16x2));
}

// v_permlane32_swap_b32: x.lanes[32:63] <-> y.lanes[0:31]; both outputs used.
__device__ __forceinline__ void pl32swap(unsigned int& x, unsigned int& y) {
    __asm__ volatile("v_permlane32_swap_b32 %0, %1" : "+v"(x), "+v"(y));
}

// async global->LDS, 16B/lane; lds base wave-uniform (lane i -> base + i*16)
__device__ __forceinline__ void glds16(const unsigned short* g, unsigned short* l) {
    __builtin_amdgcn_global_load_lds(
        (const __attribute__((address_space(1))) unsigned int*)g,
        (__attribute__((address_space(3))) unsigned int*)l, 16, 0, 0);
}

// ---------------------------------------------------------------- projection
// grid = 1536: blockIdx = ((p*2 + b)*128 + st)*2 + hh.
// Block: 16 seq rows (st) x 8 heads (hh half) x one projection p.
__global__ __launch_bounds__(256) void proj_kernel(
    const float* __restrict__ xq, const float* __restrict__ xk, const float* __restrict__ xv,
    const float* __restrict__ Wq, const float* __restrict__ bq,
    const float* __restrict__ Wk, const float* __restrict__ bk,
    const float* __restrict__ Wv, const float* __restrict__ bv,
    unsigned short* __restrict__ qb, unsigned short* __restrict__ kb,
    unsigned short* __restrict__ vtb)
{
    __shared__ __align__(16) unsigned short Wb[64 * 72];   // W bf16, stride 72
    __shared__ __align__(16) unsigned short Xb[8 * 1160];  // [h][s=16][72], h-stride padded
    __shared__ __align__(16) unsigned short Ob[12288];     // q/k: [h][s][f] h-str 1160 | V: [h][f][24] h-str 1536
    __shared__ float blds[64];

    const int t  = threadIdx.x;
    const int bi = blockIdx.x;
    const int hh = bi & 1;
    const int st = (bi >> 1) & 127;
    const int b  = (bi >> 8) & 1;
    const int p  = bi >> 9;
    const int h0 = hh * 8;
    const int lane = t & 63, w = t >> 6, quad = lane >> 4, l16 = lane & 15;

    const float* x    = (p == 0) ? xq : (p == 1) ? xk : xv;
    const float* W    = (p == 0) ? Wq : (p == 1) ? Wk : Wv;
    const float* bias = (p == 0) ? bq : (p == 1) ? bk : bv;

    // stage X: 16 rows x (8 heads x 64 e) -- 2KB contiguous per row
    #pragma unroll
    for (int i = 0; i < 8; ++i) {
        int idx = i * 256 + t;
        int s = idx >> 7, rem = idx & 127, h = rem >> 4, e4 = (rem & 15) * 4;
        floatx4 xv4 = *(const floatx4*)(x + ((size_t)(b * SEQ + st * 16 + s) * NH + h0 + h) * DE + e4);
        *(ushortx4*)&Xb[h * 1160 + s * 72 + e4] = cvt4(xv4);
    }
    // stage W
    #pragma unroll
    for (int i = 0; i < 4; ++i) {
        int idx = i * 256 + t;
        int row = idx >> 4, c4 = (idx & 15) * 4;
        floatx4 wv4 = *(const floatx4*)(W + row * 64 + c4);
        *(ushortx4*)&Wb[row * 72 + c4] = cvt4(wv4);
    }
    if (t < 64) blds[t] = bias[t];
    __syncthreads();

    if (p < 2) {
        // A = W rows (m = f, wave's f-block), B = X rows (n = s) -> D[f][s]
        bf16x8 a0 = *(const bf16x8*)&Wb[(w * 16 + l16) * 72 + quad * 8];
        bf16x8 a1 = *(const bf16x8*)&Wb[(w * 16 + l16) * 72 + 32 + quad * 8];
        floatx4 bf4 = *(const floatx4*)&blds[w * 16 + quad * 4];
        const float scale = (p == 0) ? 0.125f * LOG2E : 1.0f;  // Q in log2 domain
        #pragma unroll
        for (int h = 0; h < 8; ++h) {
            bf16x8 b0 = *(const bf16x8*)&Xb[h * 1160 + l16 * 72 + quad * 8];
            bf16x8 b1 = *(const bf16x8*)&Xb[h * 1160 + l16 * 72 + 32 + quad * 8];
            floatx4 c = {0.f, 0.f, 0.f, 0.f};
            c = __builtin_amdgcn_mfma_f32_16x16x32_bf16(a0, b0, c, 0, 0, 0);
            c = __builtin_amdgcn_mfma_f32_16x16x32_bf16(a1, b1, c, 0, 0, 0);
            floatx4 v;
            v[0] = (c[0] + bf4[0]) * scale; v[1] = (c[1] + bf4[1]) * scale;
            v[2] = (c[2] + bf4[2]) * scale; v[3] = (c[3] + bf4[3]) * scale;
            // D col = s = l16, rows f = w*16+quad*4+r -> Ob[h][s][f] (contig in f)
            *(ushortx4*)&Ob[h * 1160 + l16 * 72 + w * 16 + quad * 4] = cvt4(v);
        }
    } else {
        // A = X rows (m = s), B = W rows (n = f, wave's f-block) -> D[s][f]
        bf16x8 b0 = *(const bf16x8*)&Wb[(w * 16 + l16) * 72 + quad * 8];
        bf16x8 b1 = *(const bf16x8*)&Wb[(w * 16 + l16) * 72 + 32 + quad * 8];
        const float bw = blds[w * 16 + l16];
        #pragma unroll
        for (int h = 0; h < 8; ++h) {
            bf16x8 a0 = *(const bf16x8*)&Xb[h * 1160 + l16 * 72 + quad * 8];
            bf16x8 a1 = *(const bf16x8*)&Xb[h * 1160 + l16 * 72 + 32 + quad * 8];
            floatx4 c = {0.f, 0.f, 0.f, 0.f};
            c = __builtin_amdgcn_mfma_f32_16x16x32_bf16(a0, b0, c, 0, 0, 0);
            c = __builtin_amdgcn_mfma_f32_16x16x32_bf16(a1, b1, c, 0, 0, 0);
            floatx4 v;
            v[0] = c[0] + bw; v[1] = c[1] + bw; v[2] = c[2] + bw; v[3] = c[3] + bw;
            // D col = f = w*16+l16, rows s = quad*4+r -> ObV[h][f][24] (16B-aligned rows)
            *(ushortx4*)&Ob[h * 1536 + (w * 16 + l16) * 24 + quad * 4] = cvt4(v);
        }
    }
    __syncthreads();

    if (p < 2) {
        unsigned short* dst = (p == 0) ? qb : kb;
        #pragma unroll
        for (int i = 0; i < 4; ++i) {
            int idx = i * 256 + t;
            int c = idx & 7, s = (idx >> 3) & 15, h = idx >> 7;
            ushortx8 v = *(const ushortx8*)&Ob[h * 1160 + s * 72 + c * 8];
            *(ushortx8*)(dst + ((size_t)(b * 16 + h0 + h) * SEQ + st * 16 + s) * 64
                         + ((c ^ (s & 7)) * 8)) = v;
        }
    } else {
        #pragma unroll
        for (int i = 0; i < 4; ++i) {
            int idx = i * 256 + t;
            int cl = idx & 1, e = (idx >> 1) & 63, h = idx >> 7;
            ushortx8 v = *(const ushortx8*)&Ob[h * 1536 + e * 24 + cl * 8];
            int c = (st & 3) * 2 + cl;
            *(ushortx8*)(vtb + ((size_t)(b * 16 + h0 + h) * 64 + e) * SEQ
                         + (st >> 2) * 64 + ((c ^ (e & 7)) * 8)) = v;
        }
    }
}

// ---------------------------------------------------------------- attention
// grid = (SEQ/128, BATCH*NH); block = 512 = 8 waves.  (R6 structure, verbatim)
// wave w: qw = w&3 owns q-block qw*32..+31; kblk = w>>2 owns keys
// kblk*32..+31 of each 64-key tile. Partial O/l summed in epilogue.
__global__ __launch_bounds__(512, 4) void attn_kernel(
    const unsigned short* __restrict__ qb, const unsigned short* __restrict__ kb,
    const unsigned short* __restrict__ vtb, const int* __restrict__ mask,
    float* __restrict__ out)
{
    // Kl dbuf 16KB | Vl dbuf 16KB | Pq 16KB (Q stage) | Ml 512B
    __shared__ __align__(16) char smem[16384 + 16384 + 16384 + 512];
    unsigned short* Kl = (unsigned short*)smem;                 // [2][64*64]
    unsigned short* Vl = (unsigned short*)(smem + 16384);       // [2][64*64]
    unsigned short* Pq = (unsigned short*)(smem + 32768);       // 128*64 Q
    float*          Ml = (float*)(smem + 49152);                // [2][64]
    float*          Ol = (float*)smem;                          // epilogue 128*LDOF
    float*          Ll = (float*)(smem + 34816);                // epilogue 128*4

    const int t  = threadIdx.x;
    const int qt = blockIdx.x, bh = blockIdx.y;
    const int b  = bh >> 4, h = bh & 15;
    const int q0 = qt * 128;
    const int lane = t & 63, w = t >> 6;            // w in 0..7
    const int hi = lane >> 5, l31 = lane & 31;
    const int qw = w & 3, kblk = w >> 2;
    const int sw7 = l31 & 7;                        // row-swizzle key

    const unsigned short* kbase = kb + (size_t)bh * SEQ * DE;
    const unsigned short* vbase = vtb + (size_t)bh * DE * SEQ;
    const unsigned short* qsrc  = qb + ((size_t)bh * SEQ + q0) * DE;
    const int* mrow = mask + b * SEQ;

    // stage Q (2 loads/wave), K/V tile 0 (1+1 loads/wave) -- straight copies
    glds16(qsrc + (w * 16) * DE + lane * 8,      Pq + (w * 16) * 64);
    glds16(qsrc + (w * 16 + 8) * DE + lane * 8,  Pq + (w * 16 + 8) * 64);
    glds16(kbase + (size_t)(w * 8) * DE + lane * 8, Kl + w * 512);
    glds16(vbase + (size_t)(w * 8 + (lane >> 3)) * SEQ + (lane & 7) * 8, Vl + w * 512);
    if (t < 64) Ml[t] = mrow[t] ? -CSHIFT : -1e30f;  // CSHIFT folded into bias
    int mreg = (t < 64) ? mrow[64 + t] : 0;          // mask for tile 1
    __syncthreads();                                 // drains vmcnt -> Q/K/V in LDS

    // hoist Q B-fragments: Q[col=q=qw*32+l31][k=e = ks*16 + hi*8 + j]
    bf16x8 qf[4];
    #pragma unroll
    for (int ks = 0; ks < 4; ++ks)
        qf[ks] = *(const bf16x8*)&Pq[(qw * 32 + l31) * 64 + (((ks * 2 + hi) ^ sw7) * 8)];

    floatx16 o0, o1;                                // D[col=q][row=e], e-blocks 0/1
    #pragma unroll
    for (int i = 0; i < 16; ++i) { o0[i] = 0.f; o1[i] = 0.f; }
    float lp = 0.f;                                 // per-lane l partial (f32)

    for (int kt = 0; kt < NKT; ++kt) {
        const int cur = kt & 1, nxt = cur ^ 1;
        const unsigned short* Kc = Kl + cur * 4096;
        const unsigned short* Vc = Vl + cur * 4096;
        const float*          Mc = Ml + cur * 64;

        if (kt + 1 < NKT) {                         // prefetch tile kt+1
            const int k1 = (kt + 1) * 64;
            glds16(kbase + (size_t)(k1 + w * 8) * DE + lane * 8, Kl + nxt * 4096 + w * 512);
            glds16(vbase + (size_t)(w * 8 + (lane >> 3)) * SEQ + k1 + (lane & 7) * 8,
                   Vl + nxt * 4096 + w * 512);
            if (t < 64) Ml[nxt * 64 + t] = mreg ? -CSHIFT : -1e30f;
            mreg = (t < 64 && kt + 2 < NKT) ? mrow[(kt + 2) * 64 + t] : 0;
        }

        // C-init = mask bias: sc reg r maps to key_local = kblk*32 + (r&3)+8*(r>>2)+4*hi
        floatx16 sc;
        #pragma unroll
        for (int g = 0; g < 4; ++g) {
            floatx4 mb = *(const floatx4*)&Mc[kblk * 32 + g * 8 + hi * 4];
            sc[4 * g + 0] = mb[0]; sc[4 * g + 1] = mb[1];
            sc[4 * g + 2] = mb[2]; sc[4 * g + 3] = mb[3];
        }
        // S^T block = K·Q^T (log2 domain): D[col=q][row=key], 32 keys of this kblk
        #pragma unroll
        for (int ks = 0; ks < 4; ++ks) {
            bf16x8 kf = *(const bf16x8*)&Kc[(kblk * 32 + l31) * 64 + (((ks * 2 + hi) ^ sw7) * 8)];
            sc = __builtin_amdgcn_mfma_f32_32x32x16_bf16(kf, qf[ks], sc, 0, 0, 0);
        }

        // P = exp2(s + bias) -- shift already in bias. l partial via f32 tree.
        #pragma unroll
        for (int r = 0; r < 16; ++r)
            sc[r] = __builtin_amdgcn_exp2f(sc[r]);
        {
            float a0 = sc[0] + sc[1],   a1 = sc[2] + sc[3];
            float a2 = sc[4] + sc[5],   a3 = sc[6] + sc[7];
            float a4 = sc[8] + sc[9],   a5 = sc[10] + sc[11];
            float a6 = sc[12] + sc[13], a7 = sc[14] + sc[15];
            lp += ((a0 + a1) + (a2 + a3)) + ((a4 + a5) + (a6 + a7));
        }

        // pack to bf16 + permlane32_swap -> PV B-frags, no LDS round-trip.
        unsigned int wd0 = pkbf16(sc[0], sc[1]),   wd1 = pkbf16(sc[2], sc[3]);
        unsigned int wd2 = pkbf16(sc[4], sc[5]),   wd3 = pkbf16(sc[6], sc[7]);
        unsigned int wd4 = pkbf16(sc[8], sc[9]),   wd5 = pkbf16(sc[10], sc[11]);
        unsigned int wd6 = pkbf16(sc[12], sc[13]), wd7 = pkbf16(sc[14], sc[15]);
        pl32swap(wd0, wd2); pl32swap(wd1, wd3);
        pl32swap(wd4, wd6); pl32swap(wd5, wd7);
        uintx4 f0v = {wd0, wd1, wd2, wd3};
        uintx4 f1v = {wd4, wd5, wd6, wd7};
        bf16x8 pf0 = __builtin_bit_cast(bf16x8, f0v);
        bf16x8 pf1 = __builtin_bit_cast(bf16x8, f1v);

        // O^T += V^T · P^T: A = V^T[row=e][k=key kblk*32+s*16+hi*8+j]
        #pragma unroll
        for (int s = 0; s < 2; ++s) {
            const bf16x8 pf = s ? pf1 : pf0;
            const int cc = ((kblk * 4 + s * 2 + hi) ^ sw7) * 8;
            bf16x8 v0 = *(const bf16x8*)&Vc[l31 * 64 + cc];
            bf16x8 v1 = *(const bf16x8*)&Vc[(32 + l31) * 64 + cc];
            o0 = __builtin_amdgcn_mfma_f32_32x32x16_bf16(v0, pf, o0, 0, 0, 0);
            o1 = __builtin_amdgcn_mfma_f32_32x32x16_bf16(v1, pf, o1, 0, 0, 0);
        }

        __syncthreads();   // prefetch landed + all frag reads of cur done
    }

    // epilogue: combine kblk pair, normalize, coalesced store.
    const int qrow = qw * 32 + l31;
    Ll[qrow * 4 + kblk * 2 + hi] = lp;
    if (kblk == 1) {
        #pragma unroll
        for (int g = 0; g < 4; ++g) {
            floatx4 t0 = {o0[4*g+0], o0[4*g+1], o0[4*g+2], o0[4*g+3]};
            *(floatx4*)&Ol[qrow * LDOF + g * 8 + hi * 4] = t0;
            floatx4 t1 = {o1[4*g+0], o1[4*g+1], o1[4*g+2], o1[4*g+3]};
            *(floatx4*)&Ol[qrow * LDOF + 32 + g * 8 + hi * 4] = t1;
        }
    }
    __syncthreads();
    if (kblk == 0) {
        floatx4 lv = *(const floatx4*)&Ll[qrow * 4];
        float invl = __builtin_amdgcn_rcpf(lv[0] + lv[1] + lv[2] + lv[3]);
        #pragma unroll
        for (int g = 0; g < 4; ++g) {
            floatx4 t0 = *(floatx4*)&Ol[qrow * LDOF + g * 8 + hi * 4];
            t0[0] = (t0[0] + o0[4*g+0]) * invl; t0[1] = (t0[1] + o0[4*g+1]) * invl;
            t0[2] = (t0[2] + o0[4*g+2]) * invl; t0[3] = (t0[3] + o0[4*g+3]) * invl;
            *(floatx4*)&Ol[qrow * LDOF + g * 8 + hi * 4] = t0;
            floatx4 t1 = *(floatx4*)&Ol[qrow * LDOF + 32 + g * 8 + hi * 4];
            t1[0] = (t1[0] + o1[4*g+0]) * invl; t1[1] = (t1[1] + o1[4*g+1]) * invl;
            t1[2] = (t1[2] + o1[4*g+2]) * invl; t1[3] = (t1[3] + o1[4*g+3]) * invl;
            *(floatx4*)&Ol[qrow * LDOF + 32 + g * 8 + hi * 4] = t1;
        }
    }
    __syncthreads();
    {
        const int quad = lane >> 4, l16 = lane & 15;
        #pragma unroll
        for (int pass = 0; pass < 4; ++pass) {
            int rl  = w * 16 + pass * 4 + quad;
            int col = l16 * 4;
            floatx4 tv = *(const floatx4*)&Ol[rl * LDOF + col];
            *(floatx4*)(out + (((size_t)b * SEQ + q0 + rl) * NH + h) * DE + col) = tv;
        }
    }
}

extern "C" void kernel_launch(void* const* d_in, const int* in_sizes, int n_in,
                              void* d_out, int out_size, void* d_ws, size_t ws_size,
                              hipStream_t stream) {
    const float* query = (const float*)d_in[0];
    const float* key   = (const float*)d_in[1];
    const float* value = (const float*)d_in[2];
    const int*   mask  = (const int*)d_in[3];
    const float* Wq = (const float*)d_in[4];
    const float* bq = (const float*)d_in[5];
    const float* Wk = (const float*)d_in[6];
    const float* bk = (const float*)d_in[7];
    const float* Wv = (const float*)d_in[8];
    const float* bv = (const float*)d_in[9];

    const size_t tensor_elems = (size_t)BATCH * NH * SEQ * DE;
    unsigned short* qb  = (unsigned short*)d_ws;
    unsigned short* kb  = qb + tensor_elems;
    unsigned short* vtb = kb + tensor_elems;

    proj_kernel<<<dim3(3 * BATCH * 128 * 2), 256, 0, stream>>>(
        query, key, value, Wq, bq, Wk, bk, Wv, bv, qb, kb, vtb);
    attn_kernel<<<dim3(SEQ / 128, BATCH * NH), 512, 0, stream>>>(
        qb, kb, vtb, mask, (float*)d_out);
}

// Round 5
// 152.007 us; speedup vs baseline: 1.0014x; 1.0014x over previous
//
#include <hip/hip_runtime.h>

// SelfAttention B=2 S=2048 H=16 E=64, fp32 in/out, bf16 MFMA internally.
// Round 10: K/V direct-from-L2, zero-barrier k-loop. R9 proved the ~100us
// residual is fixed overhead (proj rewrite didn't move total), so attn is
// the only lever. K+V per head = 512KB = L2-resident; per guide m169,
// LDS-staging L2-fit data is pure overhead. Changes:
//  (a) qb/kb/vtb stored FRAG-MAJOR: proj writes 16B chunks in exactly the
//      order attn wave lanes consume them -> every attn frag load is a
//      fully-coalesced 1KB global_load_dwordx4; no XOR swizzle anywhere.
//  (b) attn k-loop has NO LDS staging, NO double-buffer, NO barriers, no
//      vmcnt choreography: K/V frags read straight from global (L1/L2 hot;
//      per-block tile working set 16KB shared by 8 waves via L1).
//  (c) mask bias for all 32 tiles precomputed into LDS once (8KB); per-tile
//      mask vmem + mreg logic deleted. One prologue barrier total.
//  (d) XCD-aware swizzle: wg&7 -> head-group, so each XCD's L2 holds 4
//      heads (2MB <= 4MB); all 512 blocks co-resident (2/CU) for the run.
//  (e) V loads issued after QK, consumed at PV (latency hides under
//      exp2/pack); live ranges sized for <=128 VGPR (4 waves/SIMD).
// Retained: 32x32x16 MFMA, 4qw x 2kblk wave split, in-register P via
// cvt_pk + permlane32_swap, fixed-shift log2-domain softmax (LOG2E folded
// into Q at proj, CSHIFT folded into mask bias), verified epilogue.

#define BATCH 2
#define SEQ   2048
#define NH    16
#define DE    64
#define LDOF  68     // O f32 epilogue stride
#define NKT   (SEQ / 64)
#define LOG2E 1.44269504088896340736f
#define CSHIFT 16.0f

using bf16x8   = __attribute__((ext_vector_type(8))) __bf16;
using bf16x4   = __attribute__((ext_vector_type(4))) __bf16;
using bf16x2   = __attribute__((ext_vector_type(2))) __bf16;
using floatx2  = __attribute__((ext_vector_type(2))) float;
using floatx4  = __attribute__((ext_vector_type(4))) float;
using floatx16 = __attribute__((ext_vector_type(16))) float;
using ushortx4 = __attribute__((ext_vector_type(4))) unsigned short;
using ushortx8 = __attribute__((ext_vector_type(8))) unsigned short;
using uintx4   = __attribute__((ext_vector_type(4))) unsigned int;
using intx4    = __attribute__((ext_vector_type(4))) int;

__device__ __forceinline__ ushortx4 cvt4(floatx4 f) {
    bf16x4 h = __builtin_convertvector(f, bf16x4);   // RNE packed cvt
    return __builtin_bit_cast(ushortx4, h);
}

__device__ __forceinline__ unsigned int pkbf16(float a, float b) {
    floatx2 f = {a, b};
    return __builtin_bit_cast(unsigned int, __builtin_convertvector(f, bf16x2));
}

// v_permlane32_swap_b32: x.lanes[32:63] <-> y.lanes[0:31]; both outputs used.
__device__ __forceinline__ void pl32swap(unsigned int& x, unsigned int& y) {
    __asm__ volatile("v_permlane32_swap_b32 %0, %1" : "+v"(x), "+v"(y));
}

// ---------------------------------------------------------------- projection
// grid = 1536: blockIdx = ((p*2 + b)*128 + st)*2 + hh.
// Block: 16 seq rows (st) x 8 heads (hh half) x one projection p.
// Outputs frag-major:
//  qb/kb chunk addr (shorts) = (bh*64 + s_glob>>5)*2048 + (e>>3)*256 + (s_glob&31)*8
//  vtb  chunk addr (shorts) = ((bh*32 + s_glob>>6)*8 + (s_glob&63)>>3)*512 + e*8
__global__ __launch_bounds__(256) void proj_kernel(
    const float* __restrict__ xq, const float* __restrict__ xk, const float* __restrict__ xv,
    const float* __restrict__ Wq, const float* __restrict__ bq,
    const float* __restrict__ Wk, const float* __restrict__ bk,
    const float* __restrict__ Wv, const float* __restrict__ bv,
    unsigned short* __restrict__ qb, unsigned short* __restrict__ kb,
    unsigned short* __restrict__ vtb)
{
    __shared__ __align__(16) unsigned short Wb[64 * 72];   // W bf16, stride 72
    __shared__ __align__(16) unsigned short Xb[8 * 1160];  // [h][s=16][72]
    __shared__ __align__(16) unsigned short Ob[12288];     // q/k: [h][s][72] | V: [h][e][24]
    __shared__ float blds[64];

    const int t  = threadIdx.x;
    const int bi = blockIdx.x;
    const int hh = bi & 1;
    const int st = (bi >> 1) & 127;
    const int b  = (bi >> 8) & 1;
    const int p  = bi >> 9;
    const int h0 = hh * 8;
    const int lane = t & 63, w = t >> 6, quad = lane >> 4, l16 = lane & 15;

    const float* x    = (p == 0) ? xq : (p == 1) ? xk : xv;
    const float* W    = (p == 0) ? Wq : (p == 1) ? Wk : Wv;
    const float* bias = (p == 0) ? bq : (p == 1) ? bk : bv;

    // stage X: 16 rows x (8 heads x 64 e) -- 2KB contiguous per row
    #pragma unroll
    for (int i = 0; i < 8; ++i) {
        int idx = i * 256 + t;
        int s = idx >> 7, rem = idx & 127, h = rem >> 4, e4 = (rem & 15) * 4;
        floatx4 xv4 = *(const floatx4*)(x + ((size_t)(b * SEQ + st * 16 + s) * NH + h0 + h) * DE + e4);
        *(ushortx4*)&Xb[h * 1160 + s * 72 + e4] = cvt4(xv4);
    }
    // stage W
    #pragma unroll
    for (int i = 0; i < 4; ++i) {
        int idx = i * 256 + t;
        int row = idx >> 4, c4 = (idx & 15) * 4;
        floatx4 wv4 = *(const floatx4*)(W + row * 64 + c4);
        *(ushortx4*)&Wb[row * 72 + c4] = cvt4(wv4);
    }
    if (t < 64) blds[t] = bias[t];
    __syncthreads();

    if (p < 2) {
        // A = W rows (m = f), B = X rows (n = s) -> D[f][s]; Ob[h][s][f]
        bf16x8 a0 = *(const bf16x8*)&Wb[(w * 16 + l16) * 72 + quad * 8];
        bf16x8 a1 = *(const bf16x8*)&Wb[(w * 16 + l16) * 72 + 32 + quad * 8];
        floatx4 bf4 = *(const floatx4*)&blds[w * 16 + quad * 4];
        const float scale = (p == 0) ? 0.125f * LOG2E : 1.0f;  // Q in log2 domain
        #pragma unroll
        for (int h = 0; h < 8; ++h) {
            bf16x8 b0 = *(const bf16x8*)&Xb[h * 1160 + l16 * 72 + quad * 8];
            bf16x8 b1 = *(const bf16x8*)&Xb[h * 1160 + l16 * 72 + 32 + quad * 8];
            floatx4 c = {0.f, 0.f, 0.f, 0.f};
            c = __builtin_amdgcn_mfma_f32_16x16x32_bf16(a0, b0, c, 0, 0, 0);
            c = __builtin_amdgcn_mfma_f32_16x16x32_bf16(a1, b1, c, 0, 0, 0);
            floatx4 v;
            v[0] = (c[0] + bf4[0]) * scale; v[1] = (c[1] + bf4[1]) * scale;
            v[2] = (c[2] + bf4[2]) * scale; v[3] = (c[3] + bf4[3]) * scale;
            *(ushortx4*)&Ob[h * 1160 + l16 * 72 + w * 16 + quad * 4] = cvt4(v);
        }
    } else {
        // A = X rows (m = s), B = W rows (n = f) -> D[s][f]; ObV[h][e][s] str 24
        bf16x8 b0 = *(const bf16x8*)&Wb[(w * 16 + l16) * 72 + quad * 8];
        bf16x8 b1 = *(const bf16x8*)&Wb[(w * 16 + l16) * 72 + 32 + quad * 8];
        const float bw = blds[w * 16 + l16];
        #pragma unroll
        for (int h = 0; h < 8; ++h) {
            bf16x8 a0 = *(const bf16x8*)&Xb[h * 1160 + l16 * 72 + quad * 8];
            bf16x8 a1 = *(const bf16x8*)&Xb[h * 1160 + l16 * 72 + 32 + quad * 8];
            floatx4 c = {0.f, 0.f, 0.f, 0.f};
            c = __builtin_amdgcn_mfma_f32_16x16x32_bf16(a0, b0, c, 0, 0, 0);
            c = __builtin_amdgcn_mfma_f32_16x16x32_bf16(a1, b1, c, 0, 0, 0);
            floatx4 v;
            v[0] = c[0] + bw; v[1] = c[1] + bw; v[2] = c[2] + bw; v[3] = c[3] + bw;
            *(ushortx4*)&Ob[h * 1536 + (w * 16 + l16) * 24 + quad * 4] = cvt4(v);
        }
    }
    __syncthreads();

    if (p < 2) {
        unsigned short* dst = (p == 0) ? qb : kb;
        const int rb  = st >> 1;             // s_glob>>5 for this tile
        const int sl0 = (st & 1) * 16;       // s_glob&31 base
        #pragma unroll
        for (int i = 0; i < 4; ++i) {
            int idx = i * 256 + t;
            int j = idx & 7, s = (idx >> 3) & 15, h = idx >> 7;
            ushortx8 v = *(const ushortx8*)&Ob[h * 1160 + s * 72 + j * 8];
            size_t off = ((size_t)((b * 16 + h0 + h) * 64) + rb) * 2048 + j * 256 + (sl0 + s) * 8;
            *(ushortx8*)(dst + off) = v;
        }
    } else {
        const int kt  = st >> 2;
        const int cb  = (st & 3) * 2;
        #pragma unroll
        for (int i = 0; i < 4; ++i) {
            int idx = i * 256 + t;
            int cl = idx & 1, e = (idx >> 1) & 63, h = idx >> 7;
            ushortx8 v = *(const ushortx8*)&Ob[h * 1536 + e * 24 + cl * 8];
            size_t off = (((size_t)(b * 16 + h0 + h) * 32 + kt) * 8 + cb + cl) * 512 + e * 8;
            *(ushortx8*)(vtb + off) = v;
        }
    }
}

// ---------------------------------------------------------------- attention
// grid = 512 (1D, XCD-swizzled); block = 512 = 8 waves.
// wave w: qw = w&3 owns q-block qw*32..+31; kblk = w>>2 owns keys
// kblk*32..+31 of each 64-key tile. K/V frags direct from global (L2-hot).
__global__ __launch_bounds__(512, 4) void attn_kernel(
    const unsigned short* __restrict__ qb, const unsigned short* __restrict__ kb,
    const unsigned short* __restrict__ vtb, const int* __restrict__ mask,
    float* __restrict__ out)
{
    // loop: Ml 8KB bias table | epilogue: Ol 34816B + Ll 2KB (disjoint)
    __shared__ __align__(16) char smem[36864 + 8192];
    float* Ol = (float*)smem;                       // 128*LDOF
    float* Ll = (float*)(smem + 34816);             // 128*4
    float* Ml = (float*)(smem + 36864);             // [NKT*64] bias

    const int wg  = blockIdx.x;
    const int bh  = ((wg >> 3) >> 4) * 8 + (wg & 7);   // XCD x holds heads {x,x+8,x+16,x+24}
    const int qt  = (wg >> 3) & 15;
    const int b   = bh >> 4, h = bh & 15;
    const int q0  = qt * 128;
    const int t   = threadIdx.x;
    const int lane = t & 63, w = t >> 6;            // w in 0..7
    const int hi = lane >> 5, l31 = lane & 31;
    const int qw = w & 3, kblk = w >> 2;

    // mask bias precompute, all 32 tiles (one pass, then single barrier)
    {
        intx4 mv = *(const intx4*)(mask + b * SEQ + t * 4);
        Ml[t * 4 + 0] = mv[0] ? -CSHIFT : -1e30f;
        Ml[t * 4 + 1] = mv[1] ? -CSHIFT : -1e30f;
        Ml[t * 4 + 2] = mv[2] ? -CSHIFT : -1e30f;
        Ml[t * 4 + 3] = mv[3] ? -CSHIFT : -1e30f;
    }

    // Q fragments direct from global (frag-major): Q[q=qw*32+l31][e=j*8..]
    const unsigned short* qp = qb + ((size_t)(bh * 64 + qt * 4 + qw)) * 2048 + hi * 256 + l31 * 8;
    bf16x8 qf[4];
    #pragma unroll
    for (int ks = 0; ks < 4; ++ks)
        qf[ks] = *(const bf16x8*)(qp + ks * 512);

    // frag-major bases: K chunk = (bh*64 + kt*2+kblk)*2048 + (ks*2+hi)*256 + l31*8
    //                   V chunk = ((bh*32+kt)*8 + kblk*4+s*2+hi)*512 + (eh*32+l31)*8
    const unsigned short* kp = kb + ((size_t)(bh * 64 + kblk)) * 2048 + hi * 256 + l31 * 8;
    const unsigned short* vp = vtb + (size_t)bh * 131072 + (kblk * 4 + hi) * 512 + l31 * 8;
    const float* Mb = Ml + kblk * 32 + hi * 4;

    __syncthreads();                                // Ml ready; only barrier pre-epilogue

    floatx16 o0, o1;                                // D[col=q][row=e], e-blocks 0/1
    #pragma unroll
    for (int i = 0; i < 16; ++i) { o0[i] = 0.f; o1[i] = 0.f; }
    float lp = 0.f;                                 // per-lane l partial (f32)

    for (int kt = 0; kt < NKT; ++kt) {
        const unsigned short* kq = kp + kt * 4096;
        bf16x8 kf0 = *(const bf16x8*)(kq);
        bf16x8 kf1 = *(const bf16x8*)(kq + 512);
        bf16x8 kf2 = *(const bf16x8*)(kq + 1024);
        bf16x8 kf3 = *(const bf16x8*)(kq + 1536);

        // C-init = mask bias (LDS broadcast): reg r -> key kblk*32+(r&3)+8*(r>>2)+4*hi
        const float* Mc = Mb + kt * 64;
        floatx16 sc;
        #pragma unroll
        for (int g = 0; g < 4; ++g) {
            floatx4 mb = *(const floatx4*)(Mc + g * 8);
            sc[4 * g + 0] = mb[0]; sc[4 * g + 1] = mb[1];
            sc[4 * g + 2] = mb[2]; sc[4 * g + 3] = mb[3];
        }
        // S^T = K·Q^T (log2 domain): D[col=q][row=key]
        sc = __builtin_amdgcn_mfma_f32_32x32x16_bf16(kf0, qf[0], sc, 0, 0, 0);
        sc = __builtin_amdgcn_mfma_f32_32x32x16_bf16(kf1, qf[1], sc, 0, 0, 0);
        sc = __builtin_amdgcn_mfma_f32_32x32x16_bf16(kf2, qf[2], sc, 0, 0, 0);
        sc = __builtin_amdgcn_mfma_f32_32x32x16_bf16(kf3, qf[3], sc, 0, 0, 0);

        // V loads issued here; consumed after exp2/pack (latency hidden)
        const unsigned short* vq = vp + kt * 4096;
        bf16x8 vf00 = *(const bf16x8*)(vq);            // s=0, e 0..31
        bf16x8 vf01 = *(const bf16x8*)(vq + 256);      // s=0, e 32..63
        bf16x8 vf10 = *(const bf16x8*)(vq + 1024);     // s=1, e 0..31
        bf16x8 vf11 = *(const bf16x8*)(vq + 1280);     // s=1, e 32..63

        // P = exp2(s + bias); l partial via f32 tree.
        #pragma unroll
        for (int r = 0; r < 16; ++r)
            sc[r] = __builtin_amdgcn_exp2f(sc[r]);
        {
            float a0 = sc[0] + sc[1],   a1 = sc[2] + sc[3];
            float a2 = sc[4] + sc[5],   a3 = sc[6] + sc[7];
            float a4 = sc[8] + sc[9],   a5 = sc[10] + sc[11];
            float a6 = sc[12] + sc[13], a7 = sc[14] + sc[15];
            lp += ((a0 + a1) + (a2 + a3)) + ((a4 + a5) + (a6 + a7));
        }

        // pack to bf16 + permlane32_swap -> PV B-frags in registers.
        unsigned int wd0 = pkbf16(sc[0], sc[1]),   wd1 = pkbf16(sc[2], sc[3]);
        unsigned int wd2 = pkbf16(sc[4], sc[5]),   wd3 = pkbf16(sc[6], sc[7]);
        unsigned int wd4 = pkbf16(sc[8], sc[9]),   wd5 = pkbf16(sc[10], sc[11]);
        unsigned int wd6 = pkbf16(sc[12], sc[13]), wd7 = pkbf16(sc[14], sc[15]);
        pl32swap(wd0, wd2); pl32swap(wd1, wd3);
        pl32swap(wd4, wd6); pl32swap(wd5, wd7);
        uintx4 f0v = {wd0, wd1, wd2, wd3};
        uintx4 f1v = {wd4, wd5, wd6, wd7};
        bf16x8 pf0 = __builtin_bit_cast(bf16x8, f0v);
        bf16x8 pf1 = __builtin_bit_cast(bf16x8, f1v);

        // O^T += V^T · P^T
        o0 = __builtin_amdgcn_mfma_f32_32x32x16_bf16(vf00, pf0, o0, 0, 0, 0);
        o1 = __builtin_amdgcn_mfma_f32_32x32x16_bf16(vf01, pf0, o1, 0, 0, 0);
        o0 = __builtin_amdgcn_mfma_f32_32x32x16_bf16(vf10, pf1, o0, 0, 0, 0);
        o1 = __builtin_amdgcn_mfma_f32_32x32x16_bf16(vf11, pf1, o1, 0, 0, 0);
    }

    // epilogue: combine kblk pair, normalize, coalesced store. (verified R6 code)
    const int qrow = qw * 32 + l31;
    Ll[qrow * 4 + kblk * 2 + hi] = lp;
    if (kblk == 1) {
        #pragma unroll
        for (int g = 0; g < 4; ++g) {
            floatx4 t0 = {o0[4*g+0], o0[4*g+1], o0[4*g+2], o0[4*g+3]};
            *(floatx4*)&Ol[qrow * LDOF + g * 8 + hi * 4] = t0;
            floatx4 t1 = {o1[4*g+0], o1[4*g+1], o1[4*g+2], o1[4*g+3]};
            *(floatx4*)&Ol[qrow * LDOF + 32 + g * 8 + hi * 4] = t1;
        }
    }
    __syncthreads();
    if (kblk == 0) {
        floatx4 lv = *(const floatx4*)&Ll[qrow * 4];
        float invl = __builtin_amdgcn_rcpf(lv[0] + lv[1] + lv[2] + lv[3]);
        #pragma unroll
        for (int g = 0; g < 4; ++g) {
            floatx4 t0 = *(floatx4*)&Ol[qrow * LDOF + g * 8 + hi * 4];
            t0[0] = (t0[0] + o0[4*g+0]) * invl; t0[1] = (t0[1] + o0[4*g+1]) * invl;
            t0[2] = (t0[2] + o0[4*g+2]) * invl; t0[3] = (t0[3] + o0[4*g+3]) * invl;
            *(floatx4*)&Ol[qrow * LDOF + g * 8 + hi * 4] = t0;
            floatx4 t1 = *(floatx4*)&Ol[qrow * LDOF + 32 + g * 8 + hi * 4];
            t1[0] = (t1[0] + o1[4*g+0]) * invl; t1[1] = (t1[1] + o1[4*g+1]) * invl;
            t1[2] = (t1[2] + o1[4*g+2]) * invl; t1[3] = (t1[3] + o1[4*g+3]) * invl;
            *(floatx4*)&Ol[qrow * LDOF + 32 + g * 8 + hi * 4] = t1;
        }
    }
    __syncthreads();
    {
        const int quad = lane >> 4, l16 = lane & 15;
        #pragma unroll
        for (int pass = 0; pass < 4; ++pass) {
            int rl  = w * 16 + pass * 4 + quad;
            int col = l16 * 4;
            floatx4 tv = *(const floatx4*)&Ol[rl * LDOF + col];
            *(floatx4*)(out + (((size_t)b * SEQ + q0 + rl) * NH + h) * DE + col) = tv;
        }
    }
}

extern "C" void kernel_launch(void* const* d_in, const int* in_sizes, int n_in,
                              void* d_out, int out_size, void* d_ws, size_t ws_size,
                              hipStream_t stream) {
    const float* query = (const float*)d_in[0];
    const float* key   = (const float*)d_in[1];
    const float* value = (const float*)d_in[2];
    const int*   mask  = (const int*)d_in[3];
    const float* Wq = (const float*)d_in[4];
    const float* bq = (const float*)d_in[5];
    const float* Wk = (const float*)d_in[6];
    const float* bk = (const float*)d_in[7];
    const float* Wv = (const float*)d_in[8];
    const float* bv = (const float*)d_in[9];

    const size_t tensor_elems = (size_t)BATCH * NH * SEQ * DE;
    unsigned short* qb  = (unsigned short*)d_ws;
    unsigned short* kb  = qb + tensor_elems;
    unsigned short* vtb = kb + tensor_elems;

    proj_kernel<<<dim3(3 * BATCH * 128 * 2), 256, 0, stream>>>(
        query, key, value, Wq, bq, Wk, bk, Wv, bv, qb, kb, vtb);
    attn_kernel<<<dim3(512), 512, 0, stream>>>(
        qb, kb, vtb, mask, (float*)d_out);
}

// Round 6
// 151.907 us; speedup vs baseline: 1.0021x; 1.0007x over previous
//
#include <hip/hip_runtime.h>

// SelfAttention B=2 S=2048 H=16 E=64, fp32 in/out, bf16 MFMA internally.
// Round 11: register-rotation prefetch. R10 proved K/V are L2/L1-resident
// (FETCH 69.7->12.4MB, conflicts ~0) yet dur didn't move: VGPR=56 shows the
// compiler loads K at the top of each tile and stalls the first QK MFMA on
// L2 latency (~200-300cy/tile/wave); the 4 same-phase waves/SIMD can't
// cover each other. Changes vs R10 (schedule only, data path identical):
//  (a) K(kt+1) frags loaded into the SAME kf regs right after QK(kt)'s last
//      use; V(kt+1) after PV(kt). One-tile-ahead rotation, zero extra VGPR,
//      wrap addressing (kt+1)&31 (tail prefetch re-reads tile 0, harmless).
//      Load latency now covered by ~300-400cy of compute per tile.
//  (b) s_setprio(1) around QK and PV MFMA clusters -- barrier-free
//      independent waves = m191's positive regime (unlike R7's lockstep).
// Retained from R10: frag-major qb/kb/vtb (coalesced 1KB frag loads), no
// LDS staging / no k-loop barriers, mask-bias table in LDS (all 32 tiles),
// XCD-aware head grouping (2MB working set per XCD L2), 32x32x16 MFMA,
// 4qw x 2kblk wave split, in-register P via cvt_pk + permlane32_swap,
// fixed-shift log2-domain softmax, verified epilogue.

#define BATCH 2
#define SEQ   2048
#define NH    16
#define DE    64
#define LDOF  68     // O f32 epilogue stride
#define NKT   (SEQ / 64)
#define LOG2E 1.44269504088896340736f
#define CSHIFT 16.0f

using bf16x8   = __attribute__((ext_vector_type(8))) __bf16;
using bf16x4   = __attribute__((ext_vector_type(4))) __bf16;
using bf16x2   = __attribute__((ext_vector_type(2))) __bf16;
using floatx2  = __attribute__((ext_vector_type(2))) float;
using floatx4  = __attribute__((ext_vector_type(4))) float;
using floatx16 = __attribute__((ext_vector_type(16))) float;
using ushortx4 = __attribute__((ext_vector_type(4))) unsigned short;
using ushortx8 = __attribute__((ext_vector_type(8))) unsigned short;
using uintx4   = __attribute__((ext_vector_type(4))) unsigned int;
using intx4    = __attribute__((ext_vector_type(4))) int;

__device__ __forceinline__ ushortx4 cvt4(floatx4 f) {
    bf16x4 h = __builtin_convertvector(f, bf16x4);   // RNE packed cvt
    return __builtin_bit_cast(ushortx4, h);
}

__device__ __forceinline__ unsigned int pkbf16(float a, float b) {
    floatx2 f = {a, b};
    return __builtin_bit_cast(unsigned int, __builtin_convertvector(f, bf16x2));
}

// v_permlane32_swap_b32: x.lanes[32:63] <-> y.lanes[0:31]; both outputs used.
__device__ __forceinline__ void pl32swap(unsigned int& x, unsigned int& y) {
    __asm__ volatile("v_permlane32_swap_b32 %0, %1" : "+v"(x), "+v"(y));
}

// ---------------------------------------------------------------- projection
// grid = 1536: blockIdx = ((p*2 + b)*128 + st)*2 + hh.
// Block: 16 seq rows (st) x 8 heads (hh half) x one projection p.
// Outputs frag-major:
//  qb/kb chunk addr (shorts) = (bh*64 + s_glob>>5)*2048 + (e>>3)*256 + (s_glob&31)*8
//  vtb  chunk addr (shorts) = ((bh*32 + s_glob>>6)*8 + (s_glob&63)>>3)*512 + e*8
__global__ __launch_bounds__(256) void proj_kernel(
    const float* __restrict__ xq, const float* __restrict__ xk, const float* __restrict__ xv,
    const float* __restrict__ Wq, const float* __restrict__ bq,
    const float* __restrict__ Wk, const float* __restrict__ bk,
    const float* __restrict__ Wv, const float* __restrict__ bv,
    unsigned short* __restrict__ qb, unsigned short* __restrict__ kb,
    unsigned short* __restrict__ vtb)
{
    __shared__ __align__(16) unsigned short Wb[64 * 72];   // W bf16, stride 72
    __shared__ __align__(16) unsigned short Xb[8 * 1160];  // [h][s=16][72]
    __shared__ __align__(16) unsigned short Ob[12288];     // q/k: [h][s][72] | V: [h][e][24]
    __shared__ float blds[64];

    const int t  = threadIdx.x;
    const int bi = blockIdx.x;
    const int hh = bi & 1;
    const int st = (bi >> 1) & 127;
    const int b  = (bi >> 8) & 1;
    const int p  = bi >> 9;
    const int h0 = hh * 8;
    const int lane = t & 63, w = t >> 6, quad = lane >> 4, l16 = lane & 15;

    const float* x    = (p == 0) ? xq : (p == 1) ? xk : xv;
    const float* W    = (p == 0) ? Wq : (p == 1) ? Wk : Wv;
    const float* bias = (p == 0) ? bq : (p == 1) ? bk : bv;

    // stage X: 16 rows x (8 heads x 64 e) -- 2KB contiguous per row
    #pragma unroll
    for (int i = 0; i < 8; ++i) {
        int idx = i * 256 + t;
        int s = idx >> 7, rem = idx & 127, h = rem >> 4, e4 = (rem & 15) * 4;
        floatx4 xv4 = *(const floatx4*)(x + ((size_t)(b * SEQ + st * 16 + s) * NH + h0 + h) * DE + e4);
        *(ushortx4*)&Xb[h * 1160 + s * 72 + e4] = cvt4(xv4);
    }
    // stage W
    #pragma unroll
    for (int i = 0; i < 4; ++i) {
        int idx = i * 256 + t;
        int row = idx >> 4, c4 = (idx & 15) * 4;
        floatx4 wv4 = *(const floatx4*)(W + row * 64 + c4);
        *(ushortx4*)&Wb[row * 72 + c4] = cvt4(wv4);
    }
    if (t < 64) blds[t] = bias[t];
    __syncthreads();

    if (p < 2) {
        // A = W rows (m = f), B = X rows (n = s) -> D[f][s]; Ob[h][s][f]
        bf16x8 a0 = *(const bf16x8*)&Wb[(w * 16 + l16) * 72 + quad * 8];
        bf16x8 a1 = *(const bf16x8*)&Wb[(w * 16 + l16) * 72 + 32 + quad * 8];
        floatx4 bf4 = *(const floatx4*)&blds[w * 16 + quad * 4];
        const float scale = (p == 0) ? 0.125f * LOG2E : 1.0f;  // Q in log2 domain
        #pragma unroll
        for (int h = 0; h < 8; ++h) {
            bf16x8 b0 = *(const bf16x8*)&Xb[h * 1160 + l16 * 72 + quad * 8];
            bf16x8 b1 = *(const bf16x8*)&Xb[h * 1160 + l16 * 72 + 32 + quad * 8];
            floatx4 c = {0.f, 0.f, 0.f, 0.f};
            c = __builtin_amdgcn_mfma_f32_16x16x32_bf16(a0, b0, c, 0, 0, 0);
            c = __builtin_amdgcn_mfma_f32_16x16x32_bf16(a1, b1, c, 0, 0, 0);
            floatx4 v;
            v[0] = (c[0] + bf4[0]) * scale; v[1] = (c[1] + bf4[1]) * scale;
            v[2] = (c[2] + bf4[2]) * scale; v[3] = (c[3] + bf4[3]) * scale;
            *(ushortx4*)&Ob[h * 1160 + l16 * 72 + w * 16 + quad * 4] = cvt4(v);
        }
    } else {
        // A = X rows (m = s), B = W rows (n = f) -> D[s][f]; ObV[h][e][s] str 24
        bf16x8 b0 = *(const bf16x8*)&Wb[(w * 16 + l16) * 72 + quad * 8];
        bf16x8 b1 = *(const bf16x8*)&Wb[(w * 16 + l16) * 72 + 32 + quad * 8];
        const float bw = blds[w * 16 + l16];
        #pragma unroll
        for (int h = 0; h < 8; ++h) {
            bf16x8 a0 = *(const bf16x8*)&Xb[h * 1160 + l16 * 72 + quad * 8];
            bf16x8 a1 = *(const bf16x8*)&Xb[h * 1160 + l16 * 72 + 32 + quad * 8];
            floatx4 c = {0.f, 0.f, 0.f, 0.f};
            c = __builtin_amdgcn_mfma_f32_16x16x32_bf16(a0, b0, c, 0, 0, 0);
            c = __builtin_amdgcn_mfma_f32_16x16x32_bf16(a1, b1, c, 0, 0, 0);
            floatx4 v;
            v[0] = c[0] + bw; v[1] = c[1] + bw; v[2] = c[2] + bw; v[3] = c[3] + bw;
            *(ushortx4*)&Ob[h * 1536 + (w * 16 + l16) * 24 + quad * 4] = cvt4(v);
        }
    }
    __syncthreads();

    if (p < 2) {
        unsigned short* dst = (p == 0) ? qb : kb;
        const int rb  = st >> 1;             // s_glob>>5 for this tile
        const int sl0 = (st & 1) * 16;       // s_glob&31 base
        #pragma unroll
        for (int i = 0; i < 4; ++i) {
            int idx = i * 256 + t;
            int j = idx & 7, s = (idx >> 3) & 15, h = idx >> 7;
            ushortx8 v = *(const ushortx8*)&Ob[h * 1160 + s * 72 + j * 8];
            size_t off = ((size_t)((b * 16 + h0 + h) * 64) + rb) * 2048 + j * 256 + (sl0 + s) * 8;
            *(ushortx8*)(dst + off) = v;
        }
    } else {
        const int kt  = st >> 2;
        const int cb  = (st & 3) * 2;
        #pragma unroll
        for (int i = 0; i < 4; ++i) {
            int idx = i * 256 + t;
            int cl = idx & 1, e = (idx >> 1) & 63, h = idx >> 7;
            ushortx8 v = *(const ushortx8*)&Ob[h * 1536 + e * 24 + cl * 8];
            size_t off = (((size_t)(b * 16 + h0 + h) * 32 + kt) * 8 + cb + cl) * 512 + e * 8;
            *(ushortx8*)(vtb + off) = v;
        }
    }
}

// ---------------------------------------------------------------- attention
// grid = 512 (1D, XCD-swizzled); block = 512 = 8 waves.
// wave w: qw = w&3 owns q-block qw*32..+31; kblk = w>>2 owns keys
// kblk*32..+31 of each 64-key tile. K/V frags direct from global (L2-hot),
// register-rotation prefetched one tile ahead.
__global__ __launch_bounds__(512, 4) void attn_kernel(
    const unsigned short* __restrict__ qb, const unsigned short* __restrict__ kb,
    const unsigned short* __restrict__ vtb, const int* __restrict__ mask,
    float* __restrict__ out)
{
    // loop: Ml 8KB bias table | epilogue: Ol 34816B + Ll 2KB (disjoint)
    __shared__ __align__(16) char smem[36864 + 8192];
    float* Ol = (float*)smem;                       // 128*LDOF
    float* Ll = (float*)(smem + 34816);             // 128*4
    float* Ml = (float*)(smem + 36864);             // [NKT*64] bias

    const int wg  = blockIdx.x;
    const int bh  = ((wg >> 3) >> 4) * 8 + (wg & 7);   // XCD x holds heads {x,x+8,x+16,x+24}
    const int qt  = (wg >> 3) & 15;
    const int b   = bh >> 4, h = bh & 15;
    const int q0  = qt * 128;
    const int t   = threadIdx.x;
    const int lane = t & 63, w = t >> 6;            // w in 0..7
    const int hi = lane >> 5, l31 = lane & 31;
    const int qw = w & 3, kblk = w >> 2;

    // mask bias precompute, all 32 tiles (one pass, then single barrier)
    {
        intx4 mv = *(const intx4*)(mask + b * SEQ + t * 4);
        Ml[t * 4 + 0] = mv[0] ? -CSHIFT : -1e30f;
        Ml[t * 4 + 1] = mv[1] ? -CSHIFT : -1e30f;
        Ml[t * 4 + 2] = mv[2] ? -CSHIFT : -1e30f;
        Ml[t * 4 + 3] = mv[3] ? -CSHIFT : -1e30f;
    }

    // Q fragments direct from global (frag-major): Q[q=qw*32+l31][e=j*8..]
    const unsigned short* qp = qb + ((size_t)(bh * 64 + qt * 4 + qw)) * 2048 + hi * 256 + l31 * 8;
    bf16x8 qf[4];
    #pragma unroll
    for (int ks = 0; ks < 4; ++ks)
        qf[ks] = *(const bf16x8*)(qp + ks * 512);

    // frag-major bases: K chunk = (bh*64 + kt*2+kblk)*2048 + (ks*2+hi)*256 + l31*8
    //                   V chunk = ((bh*32+kt)*8 + kblk*4+s*2+hi)*512 + (eh*32+l31)*8
    const unsigned short* kp = kb + ((size_t)(bh * 64 + kblk)) * 2048 + hi * 256 + l31 * 8;
    const unsigned short* vp = vtb + (size_t)bh * 131072 + (kblk * 4 + hi) * 512 + l31 * 8;
    const float* Mb = Ml + kblk * 32 + hi * 4;

    __syncthreads();                                // Ml ready; only barrier pre-epilogue

    floatx16 o0, o1;                                // D[col=q][row=e], e-blocks 0/1
    #pragma unroll
    for (int i = 0; i < 16; ++i) { o0[i] = 0.f; o1[i] = 0.f; }
    float lp = 0.f;                                 // per-lane l partial (f32)

    // prologue: tile-0 K/V frags in flight
    bf16x8 kf0 = *(const bf16x8*)(kp);
    bf16x8 kf1 = *(const bf16x8*)(kp + 512);
    bf16x8 kf2 = *(const bf16x8*)(kp + 1024);
    bf16x8 kf3 = *(const bf16x8*)(kp + 1536);
    bf16x8 vf00 = *(const bf16x8*)(vp);            // s=0, e 0..31
    bf16x8 vf01 = *(const bf16x8*)(vp + 256);      // s=0, e 32..63
    bf16x8 vf10 = *(const bf16x8*)(vp + 1024);     // s=1, e 0..31
    bf16x8 vf11 = *(const bf16x8*)(vp + 1280);     // s=1, e 32..63

    for (int kt = 0; kt < NKT; ++kt) {
        const int ktn = (kt + 1) & (NKT - 1);      // wrap: tail prefetch harmless

        // C-init = mask bias (LDS broadcast): reg r -> key kblk*32+(r&3)+8*(r>>2)+4*hi
        const float* Mc = Mb + kt * 64;
        floatx16 sc;
        #pragma unroll
        for (int g = 0; g < 4; ++g) {
            floatx4 mb = *(const floatx4*)(Mc + g * 8);
            sc[4 * g + 0] = mb[0]; sc[4 * g + 1] = mb[1];
            sc[4 * g + 2] = mb[2]; sc[4 * g + 3] = mb[3];
        }
        // S^T = K·Q^T (log2 domain): D[col=q][row=key]
        __builtin_amdgcn_s_setprio(1);
        sc = __builtin_amdgcn_mfma_f32_32x32x16_bf16(kf0, qf[0], sc, 0, 0, 0);
        sc = __builtin_amdgcn_mfma_f32_32x32x16_bf16(kf1, qf[1], sc, 0, 0, 0);
        sc = __builtin_amdgcn_mfma_f32_32x32x16_bf16(kf2, qf[2], sc, 0, 0, 0);
        sc = __builtin_amdgcn_mfma_f32_32x32x16_bf16(kf3, qf[3], sc, 0, 0, 0);
        __builtin_amdgcn_s_setprio(0);

        // rotate-prefetch K(kt+1) into the same regs (last kf use was above);
        // completes during softmax+PV (~400cy cover)
        {
            const unsigned short* kq = kp + ktn * 4096;
            kf0 = *(const bf16x8*)(kq);
            kf1 = *(const bf16x8*)(kq + 512);
            kf2 = *(const bf16x8*)(kq + 1024);
            kf3 = *(const bf16x8*)(kq + 1536);
        }

        // P = exp2(s + bias); l partial via f32 tree.
        #pragma unroll
        for (int r = 0; r < 16; ++r)
            sc[r] = __builtin_amdgcn_exp2f(sc[r]);
        {
            float a0 = sc[0] + sc[1],   a1 = sc[2] + sc[3];
            float a2 = sc[4] + sc[5],   a3 = sc[6] + sc[7];
            float a4 = sc[8] + sc[9],   a5 = sc[10] + sc[11];
            float a6 = sc[12] + sc[13], a7 = sc[14] + sc[15];
            lp += ((a0 + a1) + (a2 + a3)) + ((a4 + a5) + (a6 + a7));
        }

        // pack to bf16 + permlane32_swap -> PV B-frags in registers.
        unsigned int wd0 = pkbf16(sc[0], sc[1]),   wd1 = pkbf16(sc[2], sc[3]);
        unsigned int wd2 = pkbf16(sc[4], sc[5]),   wd3 = pkbf16(sc[6], sc[7]);
        unsigned int wd4 = pkbf16(sc[8], sc[9]),   wd5 = pkbf16(sc[10], sc[11]);
        unsigned int wd6 = pkbf16(sc[12], sc[13]), wd7 = pkbf16(sc[14], sc[15]);
        pl32swap(wd0, wd2); pl32swap(wd1, wd3);
        pl32swap(wd4, wd6); pl32swap(wd5, wd7);
        uintx4 f0v = {wd0, wd1, wd2, wd3};
        uintx4 f1v = {wd4, wd5, wd6, wd7};
        bf16x8 pf0 = __builtin_bit_cast(bf16x8, f0v);
        bf16x8 pf1 = __builtin_bit_cast(bf16x8, f1v);

        // O^T += V^T · P^T
        __builtin_amdgcn_s_setprio(1);
        o0 = __builtin_amdgcn_mfma_f32_32x32x16_bf16(vf00, pf0, o0, 0, 0, 0);
        o1 = __builtin_amdgcn_mfma_f32_32x32x16_bf16(vf01, pf0, o1, 0, 0, 0);
        o0 = __builtin_amdgcn_mfma_f32_32x32x16_bf16(vf10, pf1, o0, 0, 0, 0);
        o1 = __builtin_amdgcn_mfma_f32_32x32x16_bf16(vf11, pf1, o1, 0, 0, 0);
        __builtin_amdgcn_s_setprio(0);

        // rotate-prefetch V(kt+1) (last vf use was the PV above);
        // completes during next tile's bias/QK/softmax (~500cy cover)
        {
            const unsigned short* vq = vp + ktn * 4096;
            vf00 = *(const bf16x8*)(vq);
            vf01 = *(const bf16x8*)(vq + 256);
            vf10 = *(const bf16x8*)(vq + 1024);
            vf11 = *(const bf16x8*)(vq + 1280);
        }
    }

    // epilogue: combine kblk pair, normalize, coalesced store. (verified R6 code)
    const int qrow = qw * 32 + l31;
    Ll[qrow * 4 + kblk * 2 + hi] = lp;
    if (kblk == 1) {
        #pragma unroll
        for (int g = 0; g < 4; ++g) {
            floatx4 t0 = {o0[4*g+0], o0[4*g+1], o0[4*g+2], o0[4*g+3]};
            *(floatx4*)&Ol[qrow * LDOF + g * 8 + hi * 4] = t0;
            floatx4 t1 = {o1[4*g+0], o1[4*g+1], o1[4*g+2], o1[4*g+3]};
            *(floatx4*)&Ol[qrow * LDOF + 32 + g * 8 + hi * 4] = t1;
        }
    }
    __syncthreads();
    if (kblk == 0) {
        floatx4 lv = *(const floatx4*)&Ll[qrow * 4];
        float invl = __builtin_amdgcn_rcpf(lv[0] + lv[1] + lv[2] + lv[3]);
        #pragma unroll
        for (int g = 0; g < 4; ++g) {
            floatx4 t0 = *(floatx4*)&Ol[qrow * LDOF + g * 8 + hi * 4];
            t0[0] = (t0[0] + o0[4*g+0]) * invl; t0[1] = (t0[1] + o0[4*g+1]) * invl;
            t0[2] = (t0[2] + o0[4*g+2]) * invl; t0[3] = (t0[3] + o0[4*g+3]) * invl;
            *(floatx4*)&Ol[qrow * LDOF + g * 8 + hi * 4] = t0;
            floatx4 t1 = *(floatx4*)&Ol[qrow * LDOF + 32 + g * 8 + hi * 4];
            t1[0] = (t1[0] + o1[4*g+0]) * invl; t1[1] = (t1[1] + o1[4*g+1]) * invl;
            t1[2] = (t1[2] + o1[4*g+2]) * invl; t1[3] = (t1[3] + o1[4*g+3]) * invl;
            *(floatx4*)&Ol[qrow * LDOF + 32 + g * 8 + hi * 4] = t1;
        }
    }
    __syncthreads();
    {
        const int quad = lane >> 4, l16 = lane & 15;
        #pragma unroll
        for (int pass = 0; pass < 4; ++pass) {
            int rl  = w * 16 + pass * 4 + quad;
            int col = l16 * 4;
            floatx4 tv = *(const floatx4*)&Ol[rl * LDOF + col];
            *(floatx4*)(out + (((size_t)b * SEQ + q0 + rl) * NH + h) * DE + col) = tv;
        }
    }
}

extern "C" void kernel_launch(void* const* d_in, const int* in_sizes, int n_in,
                              void* d_out, int out_size, void* d_ws, size_t ws_size,
                              hipStream_t stream) {
    const float* query = (const float*)d_in[0];
    const float* key   = (const float*)d_in[1];
    const float* value = (const float*)d_in[2];
    const int*   mask  = (const int*)d_in[3];
    const float* Wq = (const float*)d_in[4];
    const float* bq = (const float*)d_in[5];
    const float* Wk = (const float*)d_in[6];
    const float* bk = (const float*)d_in[7];
    const float* Wv = (const float*)d_in[8];
    const float* bv = (const float*)d_in[9];

    const size_t tensor_elems = (size_t)BATCH * NH * SEQ * DE;
    unsigned short* qb  = (unsigned short*)d_ws;
    unsigned short* kb  = qb + tensor_elems;
    unsigned short* vtb = kb + tensor_elems;

    proj_kernel<<<dim3(3 * BATCH * 128 * 2), 256, 0, stream>>>(
        query, key, value, Wq, bq, Wk, bk, Wv, bv, qb, kb, vtb);
    attn_kernel<<<dim3(512), 512, 0, stream>>>(
        qb, kb, vtb, mask, (float*)d_out);
}

// Round 7
// 146.550 us; speedup vs baseline: 1.0387x; 1.0366x over previous
//
#include <hip/hip_runtime.h>

// SelfAttention B=2 S=2048 H=16 E=64, fp32 in/out, bf16 MFMA internally.
// Round 12: q=64 per wave. R11 showed all pipes ~30% with latency covered;
// the hidden limiter is the vector-memory pipe: 16 waves/CU x 32 tiles x
// 8KB = 4MB/CU at ~60B/cyc L2-hot (m56) = 70K cyc = 59% of wall. K/V
// traffic scales ONLY with q-rows-per-wave, so each wave now owns q=64
// (two 32-q column blocks a/b sharing kf/vf/mb regs): per wave-tile 8KB
// loaded, 16 MFMAs = 64 FLOP/B (2x R11) -> 2MB/CU ~= 35K cyc.
// Block = 8 waves (4 qw x 2 kblk) covers q=256; grid = 32bh x 8qt = 256
// blocks = 1/CU, 2 waves/SIMD (VGPR ~220, capped 256 via launch_bounds).
// Retained from R11: frag-major qb/kb/vtb, zero-barrier k-loop, rotation
// prefetch (K+bias after QK, V after PV), setprio on MFMA clusters,
// mask-bias table in LDS, XCD head pinning (4 heads = 2MB per XCD L2),
// in-register P via cvt_pk + permlane32_swap, fixed-shift log2 softmax.

#define BATCH 2
#define SEQ   2048
#define NH    16
#define DE    64
#define LDOF  68     // O f32 epilogue stride
#define NKT   (SEQ / 64)
#define LOG2E 1.44269504088896340736f
#define CSHIFT 16.0f

using bf16x8   = __attribute__((ext_vector_type(8))) __bf16;
using bf16x4   = __attribute__((ext_vector_type(4))) __bf16;
using bf16x2   = __attribute__((ext_vector_type(2))) __bf16;
using floatx2  = __attribute__((ext_vector_type(2))) float;
using floatx4  = __attribute__((ext_vector_type(4))) float;
using floatx16 = __attribute__((ext_vector_type(16))) float;
using ushortx4 = __attribute__((ext_vector_type(4))) unsigned short;
using ushortx8 = __attribute__((ext_vector_type(8))) unsigned short;
using uintx4   = __attribute__((ext_vector_type(4))) unsigned int;
using intx4    = __attribute__((ext_vector_type(4))) int;

__device__ __forceinline__ ushortx4 cvt4(floatx4 f) {
    bf16x4 h = __builtin_convertvector(f, bf16x4);   // RNE packed cvt
    return __builtin_bit_cast(ushortx4, h);
}

__device__ __forceinline__ unsigned int pkbf16(float a, float b) {
    floatx2 f = {a, b};
    return __builtin_bit_cast(unsigned int, __builtin_convertvector(f, bf16x2));
}

// v_permlane32_swap_b32: x.lanes[32:63] <-> y.lanes[0:31]; both outputs used.
__device__ __forceinline__ void pl32swap(unsigned int& x, unsigned int& y) {
    __asm__ volatile("v_permlane32_swap_b32 %0, %1" : "+v"(x), "+v"(y));
}

// ---------------------------------------------------------------- projection
// grid = 1536: blockIdx = ((p*2 + b)*128 + st)*2 + hh.  (unchanged from R11)
// Outputs frag-major:
//  qb/kb chunk addr (shorts) = (bh*64 + s_glob>>5)*2048 + (e>>3)*256 + (s_glob&31)*8
//  vtb  chunk addr (shorts) = ((bh*32 + s_glob>>6)*8 + (s_glob&63)>>3)*512 + e*8
__global__ __launch_bounds__(256) void proj_kernel(
    const float* __restrict__ xq, const float* __restrict__ xk, const float* __restrict__ xv,
    const float* __restrict__ Wq, const float* __restrict__ bq,
    const float* __restrict__ Wk, const float* __restrict__ bk,
    const float* __restrict__ Wv, const float* __restrict__ bv,
    unsigned short* __restrict__ qb, unsigned short* __restrict__ kb,
    unsigned short* __restrict__ vtb)
{
    __shared__ __align__(16) unsigned short Wb[64 * 72];   // W bf16, stride 72
    __shared__ __align__(16) unsigned short Xb[8 * 1160];  // [h][s=16][72]
    __shared__ __align__(16) unsigned short Ob[12288];     // q/k: [h][s][72] | V: [h][e][24]
    __shared__ float blds[64];

    const int t  = threadIdx.x;
    const int bi = blockIdx.x;
    const int hh = bi & 1;
    const int st = (bi >> 1) & 127;
    const int b  = (bi >> 8) & 1;
    const int p  = bi >> 9;
    const int h0 = hh * 8;
    const int lane = t & 63, w = t >> 6, quad = lane >> 4, l16 = lane & 15;

    const float* x    = (p == 0) ? xq : (p == 1) ? xk : xv;
    const float* W    = (p == 0) ? Wq : (p == 1) ? Wk : Wv;
    const float* bias = (p == 0) ? bq : (p == 1) ? bk : bv;

    // stage X: 16 rows x (8 heads x 64 e) -- 2KB contiguous per row
    #pragma unroll
    for (int i = 0; i < 8; ++i) {
        int idx = i * 256 + t;
        int s = idx >> 7, rem = idx & 127, h = rem >> 4, e4 = (rem & 15) * 4;
        floatx4 xv4 = *(const floatx4*)(x + ((size_t)(b * SEQ + st * 16 + s) * NH + h0 + h) * DE + e4);
        *(ushortx4*)&Xb[h * 1160 + s * 72 + e4] = cvt4(xv4);
    }
    // stage W
    #pragma unroll
    for (int i = 0; i < 4; ++i) {
        int idx = i * 256 + t;
        int row = idx >> 4, c4 = (idx & 15) * 4;
        floatx4 wv4 = *(const floatx4*)(W + row * 64 + c4);
        *(ushortx4*)&Wb[row * 72 + c4] = cvt4(wv4);
    }
    if (t < 64) blds[t] = bias[t];
    __syncthreads();

    if (p < 2) {
        // A = W rows (m = f), B = X rows (n = s) -> D[f][s]; Ob[h][s][f]
        bf16x8 a0 = *(const bf16x8*)&Wb[(w * 16 + l16) * 72 + quad * 8];
        bf16x8 a1 = *(const bf16x8*)&Wb[(w * 16 + l16) * 72 + 32 + quad * 8];
        floatx4 bf4 = *(const floatx4*)&blds[w * 16 + quad * 4];
        const float scale = (p == 0) ? 0.125f * LOG2E : 1.0f;  // Q in log2 domain
        #pragma unroll
        for (int h = 0; h < 8; ++h) {
            bf16x8 b0 = *(const bf16x8*)&Xb[h * 1160 + l16 * 72 + quad * 8];
            bf16x8 b1 = *(const bf16x8*)&Xb[h * 1160 + l16 * 72 + 32 + quad * 8];
            floatx4 c = {0.f, 0.f, 0.f, 0.f};
            c = __builtin_amdgcn_mfma_f32_16x16x32_bf16(a0, b0, c, 0, 0, 0);
            c = __builtin_amdgcn_mfma_f32_16x16x32_bf16(a1, b1, c, 0, 0, 0);
            floatx4 v;
            v[0] = (c[0] + bf4[0]) * scale; v[1] = (c[1] + bf4[1]) * scale;
            v[2] = (c[2] + bf4[2]) * scale; v[3] = (c[3] + bf4[3]) * scale;
            *(ushortx4*)&Ob[h * 1160 + l16 * 72 + w * 16 + quad * 4] = cvt4(v);
        }
    } else {
        // A = X rows (m = s), B = W rows (n = f) -> D[s][f]; ObV[h][e][s] str 24
        bf16x8 b0 = *(const bf16x8*)&Wb[(w * 16 + l16) * 72 + quad * 8];
        bf16x8 b1 = *(const bf16x8*)&Wb[(w * 16 + l16) * 72 + 32 + quad * 8];
        const float bw = blds[w * 16 + l16];
        #pragma unroll
        for (int h = 0; h < 8; ++h) {
            bf16x8 a0 = *(const bf16x8*)&Xb[h * 1160 + l16 * 72 + quad * 8];
            bf16x8 a1 = *(const bf16x8*)&Xb[h * 1160 + l16 * 72 + 32 + quad * 8];
            floatx4 c = {0.f, 0.f, 0.f, 0.f};
            c = __builtin_amdgcn_mfma_f32_16x16x32_bf16(a0, b0, c, 0, 0, 0);
            c = __builtin_amdgcn_mfma_f32_16x16x32_bf16(a1, b1, c, 0, 0, 0);
            floatx4 v;
            v[0] = c[0] + bw; v[1] = c[1] + bw; v[2] = c[2] + bw; v[3] = c[3] + bw;
            *(ushortx4*)&Ob[h * 1536 + (w * 16 + l16) * 24 + quad * 4] = cvt4(v);
        }
    }
    __syncthreads();

    if (p < 2) {
        unsigned short* dst = (p == 0) ? qb : kb;
        const int rb  = st >> 1;             // s_glob>>5 for this tile
        const int sl0 = (st & 1) * 16;       // s_glob&31 base
        #pragma unroll
        for (int i = 0; i < 4; ++i) {
            int idx = i * 256 + t;
            int j = idx & 7, s = (idx >> 3) & 15, h = idx >> 7;
            ushortx8 v = *(const ushortx8*)&Ob[h * 1160 + s * 72 + j * 8];
            size_t off = ((size_t)((b * 16 + h0 + h) * 64) + rb) * 2048 + j * 256 + (sl0 + s) * 8;
            *(ushortx8*)(dst + off) = v;
        }
    } else {
        const int kt  = st >> 2;
        const int cb  = (st & 3) * 2;
        #pragma unroll
        for (int i = 0; i < 4; ++i) {
            int idx = i * 256 + t;
            int cl = idx & 1, e = (idx >> 1) & 63, h = idx >> 7;
            ushortx8 v = *(const ushortx8*)&Ob[h * 1536 + e * 24 + cl * 8];
            size_t off = (((size_t)(b * 16 + h0 + h) * 32 + kt) * 8 + cb + cl) * 512 + e * 8;
            *(ushortx8*)(vtb + off) = v;
        }
    }
}

// ---------------------------------------------------------------- attention
// grid = 256 (1D, XCD-pinned); block = 512 = 8 waves (4 qw x 2 kblk).
// wave w: owns q rows qw*64..+63 (two 32-q halves a/b), kblk half of keys.
__global__ __launch_bounds__(512, 2) void attn_kernel(
    const unsigned short* __restrict__ qb, const unsigned short* __restrict__ kb,
    const unsigned short* __restrict__ vtb, const int* __restrict__ mask,
    float* __restrict__ out)
{
    // epilogue: Ol 69632B + Ll 4KB | loop: Ml 8KB (disjoint)
    __shared__ __align__(16) char smem[69632 + 4096 + 8192];
    float* Ol = (float*)smem;                       // 256*LDOF
    float* Ll = (float*)(smem + 69632);             // 256*4
    float* Ml = (float*)(smem + 73728);             // [NKT*64] bias

    const int wg  = blockIdx.x;
    const int bh  = ((wg >> 3) >> 3) * 8 + (wg & 7);   // XCD x holds heads {x,x+8,x+16,x+24}
    const int qt  = (wg >> 3) & 7;
    const int b   = bh >> 4, h = bh & 15;
    const int q0  = qt * 256;
    const int t   = threadIdx.x;
    const int lane = t & 63, w = t >> 6;            // w in 0..7
    const int hi = lane >> 5, l31 = lane & 31;
    const int qw = w & 3, kblk = w >> 2;

    // mask bias precompute, all 32 tiles (one pass, then single barrier)
    {
        intx4 mv = *(const intx4*)(mask + b * SEQ + t * 4);
        Ml[t * 4 + 0] = mv[0] ? -CSHIFT : -1e30f;
        Ml[t * 4 + 1] = mv[1] ? -CSHIFT : -1e30f;
        Ml[t * 4 + 2] = mv[2] ? -CSHIFT : -1e30f;
        Ml[t * 4 + 3] = mv[3] ? -CSHIFT : -1e30f;
    }

    // frag-major bases
    const unsigned short* qpa = qb + ((size_t)(bh * 64 + qt * 8 + qw * 2)) * 2048 + hi * 256 + l31 * 8;
    const unsigned short* kp  = kb + ((size_t)(bh * 64 + kblk)) * 2048 + hi * 256 + l31 * 8;
    const unsigned short* vp  = vtb + (size_t)bh * 131072 + (kblk * 4 + hi) * 512 + l31 * 8;
    const float* Mb = Ml + kblk * 32 + hi * 4;

    // Q fragments for both q-halves (a: rows qw*64+l31, b: +32)
    bf16x8 qfa[4], qfb[4];
    #pragma unroll
    for (int ks = 0; ks < 4; ++ks) {
        qfa[ks] = *(const bf16x8*)(qpa + ks * 512);
        qfb[ks] = *(const bf16x8*)(qpa + 2048 + ks * 512);
    }

    __syncthreads();                                // Ml ready

    floatx16 oa0, oa1, ob0, ob1;
    #pragma unroll
    for (int i = 0; i < 16; ++i) { oa0[i] = 0.f; oa1[i] = 0.f; ob0[i] = 0.f; ob1[i] = 0.f; }
    float lpa = 0.f, lpb = 0.f;

    // prologue: tile-0 K/V frags + bias in regs
    bf16x8 kf0 = *(const bf16x8*)(kp);
    bf16x8 kf1 = *(const bf16x8*)(kp + 512);
    bf16x8 kf2 = *(const bf16x8*)(kp + 1024);
    bf16x8 kf3 = *(const bf16x8*)(kp + 1536);
    bf16x8 vf00 = *(const bf16x8*)(vp);            // s=0, e 0..31
    bf16x8 vf01 = *(const bf16x8*)(vp + 256);      // s=0, e 32..63
    bf16x8 vf10 = *(const bf16x8*)(vp + 1024);     // s=1, e 0..31
    bf16x8 vf11 = *(const bf16x8*)(vp + 1280);     // s=1, e 32..63
    floatx4 mb0 = *(const floatx4*)(Mb);
    floatx4 mb1 = *(const floatx4*)(Mb + 8);
    floatx4 mb2 = *(const floatx4*)(Mb + 16);
    floatx4 mb3 = *(const floatx4*)(Mb + 24);

    for (int kt = 0; kt < NKT; ++kt) {
        const int ktn = (kt + 1) & (NKT - 1);      // wrap: tail prefetch harmless

        // C-init = mask bias (regs, prefetched): reg r -> key kblk*32+(r&3)+8*(r>>2)+4*hi
        floatx16 sa, sb;
        #pragma unroll
        for (int j = 0; j < 4; ++j) {
            sa[j]      = mb0[j]; sb[j]      = mb0[j];
            sa[4 + j]  = mb1[j]; sb[4 + j]  = mb1[j];
            sa[8 + j]  = mb2[j]; sb[8 + j]  = mb2[j];
            sa[12 + j] = mb3[j]; sb[12 + j] = mb3[j];
        }
        // S^T = K·Q^T (log2 domain), both q-halves share kf
        __builtin_amdgcn_s_setprio(1);
        sa = __builtin_amdgcn_mfma_f32_32x32x16_bf16(kf0, qfa[0], sa, 0, 0, 0);
        sa = __builtin_amdgcn_mfma_f32_32x32x16_bf16(kf1, qfa[1], sa, 0, 0, 0);
        sa = __builtin_amdgcn_mfma_f32_32x32x16_bf16(kf2, qfa[2], sa, 0, 0, 0);
        sa = __builtin_amdgcn_mfma_f32_32x32x16_bf16(kf3, qfa[3], sa, 0, 0, 0);
        sb = __builtin_amdgcn_mfma_f32_32x32x16_bf16(kf0, qfb[0], sb, 0, 0, 0);
        sb = __builtin_amdgcn_mfma_f32_32x32x16_bf16(kf1, qfb[1], sb, 0, 0, 0);
        sb = __builtin_amdgcn_mfma_f32_32x32x16_bf16(kf2, qfb[2], sb, 0, 0, 0);
        sb = __builtin_amdgcn_mfma_f32_32x32x16_bf16(kf3, qfb[3], sb, 0, 0, 0);
        __builtin_amdgcn_s_setprio(0);

        // rotate-prefetch K(kt+1) + bias(kt+1); consumed next tile (~600cy cover)
        {
            const unsigned short* kq = kp + ktn * 4096;
            kf0 = *(const bf16x8*)(kq);
            kf1 = *(const bf16x8*)(kq + 512);
            kf2 = *(const bf16x8*)(kq + 1024);
            kf3 = *(const bf16x8*)(kq + 1536);
            const float* Mn = Mb + ktn * 64;
            mb0 = *(const floatx4*)(Mn);
            mb1 = *(const floatx4*)(Mn + 8);
            mb2 = *(const floatx4*)(Mn + 16);
            mb3 = *(const floatx4*)(Mn + 24);
        }

        // P = exp2(s + bias); l partials
        #pragma unroll
        for (int r = 0; r < 16; ++r) sa[r] = __builtin_amdgcn_exp2f(sa[r]);
        #pragma unroll
        for (int r = 0; r < 16; ++r) sb[r] = __builtin_amdgcn_exp2f(sb[r]);
        {
            float a0 = sa[0] + sa[1],   a1 = sa[2] + sa[3];
            float a2 = sa[4] + sa[5],   a3 = sa[6] + sa[7];
            float a4 = sa[8] + sa[9],   a5 = sa[10] + sa[11];
            float a6 = sa[12] + sa[13], a7 = sa[14] + sa[15];
            lpa += ((a0 + a1) + (a2 + a3)) + ((a4 + a5) + (a6 + a7));
            float b0 = sb[0] + sb[1],   b1 = sb[2] + sb[3];
            float b2 = sb[4] + sb[5],   b3 = sb[6] + sb[7];
            float b4 = sb[8] + sb[9],   b5 = sb[10] + sb[11];
            float b6 = sb[12] + sb[13], b7 = sb[14] + sb[15];
            lpb += ((b0 + b1) + (b2 + b3)) + ((b4 + b5) + (b6 + b7));
        }

        // pack to bf16 + permlane32_swap -> PV B-frags (per q-half)
        unsigned int a_w0 = pkbf16(sa[0], sa[1]),   a_w1 = pkbf16(sa[2], sa[3]);
        unsigned int a_w2 = pkbf16(sa[4], sa[5]),   a_w3 = pkbf16(sa[6], sa[7]);
        unsigned int a_w4 = pkbf16(sa[8], sa[9]),   a_w5 = pkbf16(sa[10], sa[11]);
        unsigned int a_w6 = pkbf16(sa[12], sa[13]), a_w7 = pkbf16(sa[14], sa[15]);
        pl32swap(a_w0, a_w2); pl32swap(a_w1, a_w3);
        pl32swap(a_w4, a_w6); pl32swap(a_w5, a_w7);
        uintx4 fa0 = {a_w0, a_w1, a_w2, a_w3};
        uintx4 fa1 = {a_w4, a_w5, a_w6, a_w7};
        bf16x8 pf0a = __builtin_bit_cast(bf16x8, fa0);
        bf16x8 pf1a = __builtin_bit_cast(bf16x8, fa1);
        unsigned int b_w0 = pkbf16(sb[0], sb[1]),   b_w1 = pkbf16(sb[2], sb[3]);
        unsigned int b_w2 = pkbf16(sb[4], sb[5]),   b_w3 = pkbf16(sb[6], sb[7]);
        unsigned int b_w4 = pkbf16(sb[8], sb[9]),   b_w5 = pkbf16(sb[10], sb[11]);
        unsigned int b_w6 = pkbf16(sb[12], sb[13]), b_w7 = pkbf16(sb[14], sb[15]);
        pl32swap(b_w0, b_w2); pl32swap(b_w1, b_w3);
        pl32swap(b_w4, b_w6); pl32swap(b_w5, b_w7);
        uintx4 fb0 = {b_w0, b_w1, b_w2, b_w3};
        uintx4 fb1 = {b_w4, b_w5, b_w6, b_w7};
        bf16x8 pf0b = __builtin_bit_cast(bf16x8, fb0);
        bf16x8 pf1b = __builtin_bit_cast(bf16x8, fb1);

        // O^T += V^T · P^T; vf shared by both q-halves
        __builtin_amdgcn_s_setprio(1);
        oa0 = __builtin_amdgcn_mfma_f32_32x32x16_bf16(vf00, pf0a, oa0, 0, 0, 0);
        oa1 = __builtin_amdgcn_mfma_f32_32x32x16_bf16(vf01, pf0a, oa1, 0, 0, 0);
        oa0 = __builtin_amdgcn_mfma_f32_32x32x16_bf16(vf10, pf1a, oa0, 0, 0, 0);
        oa1 = __builtin_amdgcn_mfma_f32_32x32x16_bf16(vf11, pf1a, oa1, 0, 0, 0);
        ob0 = __builtin_amdgcn_mfma_f32_32x32x16_bf16(vf00, pf0b, ob0, 0, 0, 0);
        ob1 = __builtin_amdgcn_mfma_f32_32x32x16_bf16(vf01, pf0b, ob1, 0, 0, 0);
        ob0 = __builtin_amdgcn_mfma_f32_32x32x16_bf16(vf10, pf1b, ob0, 0, 0, 0);
        ob1 = __builtin_amdgcn_mfma_f32_32x32x16_bf16(vf11, pf1b, ob1, 0, 0, 0);
        __builtin_amdgcn_s_setprio(0);

        // rotate-prefetch V(kt+1); consumed next tile's PV (~800cy cover)
        {
            const unsigned short* vq = vp + ktn * 4096;
            vf00 = *(const bf16x8*)(vq);
            vf01 = *(const bf16x8*)(vq + 256);
            vf10 = *(const bf16x8*)(vq + 1024);
            vf11 = *(const bf16x8*)(vq + 1280);
        }
    }

    // epilogue: combine kblk pair, normalize, coalesced store.
    const int qa  = qw * 64 + l31;
    const int qbr = qa + 32;
    Ll[qa * 4 + kblk * 2 + hi]  = lpa;
    Ll[qbr * 4 + kblk * 2 + hi] = lpb;
    if (kblk == 1) {
        #pragma unroll
        for (int g = 0; g < 4; ++g) {
            floatx4 ta0 = {oa0[4*g+0], oa0[4*g+1], oa0[4*g+2], oa0[4*g+3]};
            *(floatx4*)&Ol[qa * LDOF + g * 8 + hi * 4] = ta0;
            floatx4 ta1 = {oa1[4*g+0], oa1[4*g+1], oa1[4*g+2], oa1[4*g+3]};
            *(floatx4*)&Ol[qa * LDOF + 32 + g * 8 + hi * 4] = ta1;
            floatx4 tb0 = {ob0[4*g+0], ob0[4*g+1], ob0[4*g+2], ob0[4*g+3]};
            *(floatx4*)&Ol[qbr * LDOF + g * 8 + hi * 4] = tb0;
            floatx4 tb1 = {ob1[4*g+0], ob1[4*g+1], ob1[4*g+2], ob1[4*g+3]};
            *(floatx4*)&Ol[qbr * LDOF + 32 + g * 8 + hi * 4] = tb1;
        }
    }
    __syncthreads();
    if (kblk == 0) {
        floatx4 lva = *(const floatx4*)&Ll[qa * 4];
        float invla = __builtin_amdgcn_rcpf(lva[0] + lva[1] + lva[2] + lva[3]);
        floatx4 lvb = *(const floatx4*)&Ll[qbr * 4];
        float invlb = __builtin_amdgcn_rcpf(lvb[0] + lvb[1] + lvb[2] + lvb[3]);
        #pragma unroll
        for (int g = 0; g < 4; ++g) {
            floatx4 ta0 = *(floatx4*)&Ol[qa * LDOF + g * 8 + hi * 4];
            ta0[0] = (ta0[0] + oa0[4*g+0]) * invla; ta0[1] = (ta0[1] + oa0[4*g+1]) * invla;
            ta0[2] = (ta0[2] + oa0[4*g+2]) * invla; ta0[3] = (ta0[3] + oa0[4*g+3]) * invla;
            *(floatx4*)&Ol[qa * LDOF + g * 8 + hi * 4] = ta0;
            floatx4 ta1 = *(floatx4*)&Ol[qa * LDOF + 32 + g * 8 + hi * 4];
            ta1[0] = (ta1[0] + oa1[4*g+0]) * invla; ta1[1] = (ta1[1] + oa1[4*g+1]) * invla;
            ta1[2] = (ta1[2] + oa1[4*g+2]) * invla; ta1[3] = (ta1[3] + oa1[4*g+3]) * invla;
            *(floatx4*)&Ol[qa * LDOF + 32 + g * 8 + hi * 4] = ta1;
            floatx4 tb0 = *(floatx4*)&Ol[qbr * LDOF + g * 8 + hi * 4];
            tb0[0] = (tb0[0] + ob0[4*g+0]) * invlb; tb0[1] = (tb0[1] + ob0[4*g+1]) * invlb;
            tb0[2] = (tb0[2] + ob0[4*g+2]) * invlb; tb0[3] = (tb0[3] + ob0[4*g+3]) * invlb;
            *(floatx4*)&Ol[qbr * LDOF + g * 8 + hi * 4] = tb0;
            floatx4 tb1 = *(floatx4*)&Ol[qbr * LDOF + 32 + g * 8 + hi * 4];
            tb1[0] = (tb1[0] + ob1[4*g+0]) * invlb; tb1[1] = (tb1[1] + ob1[4*g+1]) * invlb;
            tb1[2] = (tb1[2] + ob1[4*g+2]) * invlb; tb1[3] = (tb1[3] + ob1[4*g+3]) * invlb;
            *(floatx4*)&Ol[qbr * LDOF + 32 + g * 8 + hi * 4] = tb1;
        }
    }
    __syncthreads();
    {
        const int quad = lane >> 4, l16 = lane & 15;
        #pragma unroll
        for (int pass = 0; pass < 8; ++pass) {
            int rl  = w * 32 + pass * 4 + quad;
            int col = l16 * 4;
            floatx4 tv = *(const floatx4*)&Ol[rl * LDOF + col];
            *(floatx4*)(out + (((size_t)b * SEQ + q0 + rl) * NH + h) * DE + col) = tv;
        }
    }
}

extern "C" void kernel_launch(void* const* d_in, const int* in_sizes, int n_in,
                              void* d_out, int out_size, void* d_ws, size_t ws_size,
                              hipStream_t stream) {
    const float* query = (const float*)d_in[0];
    const float* key   = (const float*)d_in[1];
    const float* value = (const float*)d_in[2];
    const int*   mask  = (const int*)d_in[3];
    const float* Wq = (const float*)d_in[4];
    const float* bq = (const float*)d_in[5];
    const float* Wk = (const float*)d_in[6];
    const float* bk = (const float*)d_in[7];
    const float* Wv = (const float*)d_in[8];
    const float* bv = (const float*)d_in[9];

    const size_t tensor_elems = (size_t)BATCH * NH * SEQ * DE;
    unsigned short* qb  = (unsigned short*)d_ws;
    unsigned short* kb  = qb + tensor_elems;
    unsigned short* vtb = kb + tensor_elems;

    proj_kernel<<<dim3(3 * BATCH * 128 * 2), 256, 0, stream>>>(
        query, key, value, Wq, bq, Wk, bk, Wv, bv, qb, kb, vtb);
    attn_kernel<<<dim3(256), 512, 0, stream>>>(
        qb, kb, vtb, mask, (float*)d_out);
}